// Round 9
// baseline (57.666 us; speedup 1.0000x reference)
//
#include <hip/hip_runtime.h>
#include <hip/hip_cooperative_groups.h>
#include <math.h>

namespace cg = cooperative_groups;

#define NM 1024
#define NS 256
#define NK 1025
#define CS 4    // steps per chunk
#define NC 64   // chunks per sequence = lanes per wave

struct Q4 { float x, y, z, w; };

__device__ __forceinline__ Q4 qmul(const Q4 a, const Q4 b) {
    Q4 o;
    o.x = a.w*b.x + a.x*b.w + a.y*b.z - a.z*b.y;
    o.y = a.w*b.y - a.x*b.z + a.y*b.w + a.z*b.x;
    o.z = a.w*b.z + a.x*b.y - a.y*b.x + a.z*b.w;
    o.w = a.w*b.w - a.x*b.x - a.y*b.y - a.z*b.z;
    return o;
}

__device__ __forceinline__ void q2m(const Q4 q, float* R) {
    float x = q.x, y = q.y, z = q.z, w = q.w;
    R[0] = 1.f - 2.f*(y*y + z*z); R[1] = 2.f*(x*y - z*w);       R[2] = 2.f*(x*z + y*w);
    R[3] = 2.f*(x*y + z*w);       R[4] = 1.f - 2.f*(x*x + z*z); R[5] = 2.f*(y*z - x*w);
    R[6] = 2.f*(x*z - y*w);       R[7] = 2.f*(y*z + x*w);       R[8] = 1.f - 2.f*(x*x + y*y);
}

__device__ __forceinline__ void m3mul(float* o, const float* X, const float* Y) {
    #pragma unroll
    for (int r = 0; r < 3; ++r)
        #pragma unroll
        for (int c = 0; c < 3; ++c)
            o[r*3+c] = X[r*3+0]*Y[c] + X[r*3+1]*Y[3+c] + X[r*3+2]*Y[6+c];
}

__device__ __forceinline__ void m3v(float* o, const float* X, const float* v) {
    o[0] = X[0]*v[0] + X[1]*v[1] + X[2]*v[2];
    o[1] = X[3]*v[0] + X[4]*v[1] + X[5]*v[2];
    o[2] = X[6]*v[0] + X[7]*v[1] + X[8]*v[2];
}

__device__ __forceinline__ void skmul(float* o, float x, float y, float z, const float* M) {
    #pragma unroll
    for (int c = 0; c < 3; ++c) {
        float m0 = M[c], m1 = M[3+c], m2 = M[6+c];
        o[c]   = -z*m1 + y*m2;
        o[3+c] =  z*m0 - x*m2;
        o[6+c] = -y*m0 + x*m1;
    }
}

__device__ __forceinline__ void crossv(float* o, float x, float y, float z, const float* v) {
    o[0] = -z*v[1] + y*v[2];
    o[1] =  z*v[0] - x*v[2];
    o[2] = -y*v[0] + x*v[1];
}

__device__ __forceinline__ void ld12(float* dst, const float4* src) {
    float4 t0 = src[0], t1 = src[1], t2 = src[2];
    dst[0]=t0.x; dst[1]=t0.y; dst[2] =t0.z; dst[3] =t0.w;
    dst[4]=t1.x; dst[5]=t1.y; dst[6] =t1.z; dst[7] =t1.w;
    dst[8]=t2.x; dst[9]=t2.y; dst[10]=t2.z; dst[11]=t2.w;
}

// ------------------------------------------------------------------
// Fused kernel: 64 blocks x 1024 threads (cooperative).
// Phase 1: wave-per-sequence (16 per block), bias-contracted scan
// formulation (verified R8). grid.sync(). Phase 2: block 0 only.
// ------------------------------------------------------------------
__global__ __launch_bounds__(1024, 4) void imu_fused(
    const float* __restrict__ acc, const float* __restrict__ gyro,
    const float* __restrict__ dt, const float* __restrict__ bias_a,
    const float* __restrict__ bias_w, float* __restrict__ ws,
    const float* __restrict__ g, const float* __restrict__ init_rot,
    const float* __restrict__ init_pos, const float* __restrict__ init_vel,
    const float* __restrict__ gt_rot, const float* __restrict__ gt_pos,
    const float* __restrict__ gt_vel, float* __restrict__ out)
{
    // phase-2 LDS (used by block 0 only; 41.6 KB)
    __shared__ float4 srot[NK];
    __shared__ float  svel[NK][3];
    __shared__ float  spos[NK][3];
    __shared__ float4 qtot[16];
    __shared__ float  vtot[16][3];
    __shared__ float  ptot[16][3];

    float* g_gamma = ws;            // NM*4
    float* g_beta  = ws + 4*NM;     // NM*3
    float* g_alpha = ws + 7*NM;     // NM*3
    float* g_kf    = ws + 10*NM;    // NM

    // ================= PHASE 1 =================
    {
        const int lane = threadIdx.x & 63;
        const int m    = blockIdx.x * 16 + (threadIdx.x >> 6);
        const int c    = lane;

        float av[12], gv[12], bav[12], bwv[12], dtv[4];
        ld12(av,  (const float4*)(acc    + (size_t)m*NS*3) + c*3);
        ld12(gv,  (const float4*)(gyro   + (size_t)m*NS*3) + c*3);
        ld12(bav, (const float4*)(bias_a + (size_t)m*NS*3) + c*3);
        ld12(bwv, (const float4*)(bias_w + (size_t)m*NS*3) + c*3);
        {
            float4 t = ((const float4*)(dt + (size_t)m*NS))[c];
            dtv[0]=t.x; dtv[1]=t.y; dtv[2]=t.z; dtv[3]=t.w;
        }

        float ba0[3], bw0[3];
        ba0[0] = __shfl(bav[0], 0, 64); ba0[1] = __shfl(bav[1], 0, 64); ba0[2] = __shfl(bav[2], 0, 64);
        bw0[0] = __shfl(bwv[0], 0, 64); bw0[1] = __shfl(bwv[1], 0, 64); bw0[2] = __shfl(bwv[2], 0, 64);

        Q4 fq = {0.f, 0.f, 0.f, 1.f};
        float G[9] = {1.f,0.f,0.f, 0.f,1.f,0.f, 0.f,0.f,1.f};
        float T = 0.f;
        float u[3] = {0.f}, z[3] = {0.f};
        float A[9]  = {1.f,0.f,0.f, 0.f,1.f,0.f, 0.f,0.f,1.f};
        float Bmv[3] = {0.f};
        float M1v[3] = {0.f}, N[9] = {0.f}, nnv[3] = {0.f};
        float K1v[3] = {0.f}, K2a[9] = {0.f}, k2bv[3] = {0.f};

        #pragma unroll
        for (int j = 0; j < CS; ++j) {
            float d  = dtv[j];
            float ax = av[j*3+0], ay = av[j*3+1], az = av[j*3+2];
            float gx = gv[j*3+0], gy = gv[j*3+1], gz = gv[j*3+2];
            float abx = ax - bav[j*3+0], aby = ay - bav[j*3+1], abz = az - bav[j*3+2];
            float wbx = gx - bwv[j*3+0], wby = gy - bwv[j*3+1], wbz = gz - bwv[j*3+2];

            #pragma unroll
            for (int i = 0; i < 3; ++i) { K1v[i] += d*M1v[i]; k2bv[i] += d*nnv[i]; }
            #pragma unroll
            for (int i = 0; i < 9; ++i) K2a[i] += d*N[i];

            float ga0 = G[0]*ax + G[1]*ay + G[2]*az;
            float ga1 = G[3]*ax + G[4]*ay + G[5]*az;
            float ga2 = G[6]*ax + G[7]*ay + G[8]*az;
            float hd2 = 0.5f*d*d;
            z[0] += d*u[0] + hd2*ga0;
            z[1] += d*u[1] + hd2*ga1;
            z[2] += d*u[2] + hd2*ga2;
            u[0] += d*ga0; u[1] += d*ga1; u[2] += d*ga2;
            T += d;

            float phx = gx*d, phy = gy*d, phz = gz*d;
            float th2 = phx*phx + phy*phy + phz*phz;
            float k  = 0.5f - th2*(1.0f/48.0f);
            float ew = 1.0f - th2*0.125f;
            Q4 e = {phx*k, phy*k, phz*k, ew};
            fq = qmul(fq, e);
            q2m(fq, G);

            {
                float gb[3]; m3v(gb, G, ba0);
                M1v[0] += d*gb[0]; M1v[1] += d*gb[1]; M1v[2] += d*gb[2];
            }
            {
                float SA[9], GX[9];
                skmul(SA, abx, aby, abz, A);
                m3mul(GX, G, SA);
                #pragma unroll
                for (int i = 0; i < 9; ++i) N[i] += d*GX[i];
            }
            {
                float cb[3], gc[3];
                crossv(cb, abx, aby, abz, Bmv);
                m3v(gc, G, cb);
                nnv[0] += d*gc[0]; nnv[1] += d*gc[1]; nnv[2] += d*gc[2];
            }
            {
                float WA[9];
                skmul(WA, wbx, wby, wbz, A);
                #pragma unroll
                for (int i = 0; i < 9; ++i) A[i] -= d*WA[i];
            }
            {
                float cw[3];
                crossv(cw, wbx, wby, wbz, Bmv);
                Bmv[0] -= d*(cw[0] + bw0[0]);
                Bmv[1] -= d*(cw[1] + bw0[1]);
                Bmv[2] -= d*(cw[2] + bw0[2]);
            }
        }

        // scan 1: quat inclusive prefix -> final + exclusive
        Q4 qi = fq;
        #pragma unroll
        for (int off = 1; off < 64; off <<= 1) {
            Q4 y;
            y.x = __shfl_up(qi.x, off, 64);
            y.y = __shfl_up(qi.y, off, 64);
            y.z = __shfl_up(qi.z, off, 64);
            y.w = __shfl_up(qi.w, off, 64);
            if (lane >= off) qi = qmul(y, qi);
        }
        Q4 qf;
        qf.x = __shfl(qi.x, 63, 64);
        qf.y = __shfl(qi.y, 63, 64);
        qf.z = __shfl(qi.z, 63, 64);
        qf.w = __shfl(qi.w, 63, 64);
        Q4 qp;
        qp.x = __shfl_up(qi.x, 1, 64);
        qp.y = __shfl_up(qi.y, 1, 64);
        qp.z = __shfl_up(qi.z, 1, 64);
        qp.w = __shfl_up(qi.w, 1, 64);
        if (lane == 0) { qp.x = 0.f; qp.y = 0.f; qp.z = 0.f; qp.w = 1.f; }
        float R[9]; q2m(qp, R);

        // scan 2: affine (A, bvec) inclusive prefix
        float bvec[3] = {Bmv[0], Bmv[1], Bmv[2]};
        #pragma unroll
        for (int off = 1; off < 64; off <<= 1) {
            float yA[9], yb[3];
            #pragma unroll
            for (int i = 0; i < 9; ++i) yA[i] = __shfl_up(A[i], off, 64);
            yb[0] = __shfl_up(bvec[0], off, 64);
            yb[1] = __shfl_up(bvec[1], off, 64);
            yb[2] = __shfl_up(bvec[2], off, 64);
            if (lane >= off) {
                float nA[9], nb[3];
                m3mul(nA, A, yA);
                m3v(nb, A, yb);
                #pragma unroll
                for (int i = 0; i < 9; ++i) A[i] = nA[i];
                bvec[0] = nb[0] + bvec[0];
                bvec[1] = nb[1] + bvec[1];
                bvec[2] = nb[2] + bvec[2];
            }
        }
        float Q2fv[3];
        Q2fv[0] = __shfl(bvec[0], 63, 64);
        Q2fv[1] = __shfl(bvec[1], 63, 64);
        Q2fv[2] = __shfl(bvec[2], 63, 64);
        float qv[3];
        qv[0] = __shfl_up(bvec[0], 1, 64);
        qv[1] = __shfl_up(bvec[1], 1, 64);
        qv[2] = __shfl_up(bvec[2], 1, 64);
        if (lane == 0) { qv[0] = 0.f; qv[1] = 0.f; qv[2] = 0.f; }

        // scan 3: T inclusive suffix sum
        float S = T;
        #pragma unroll
        for (int off = 1; off < 64; off <<= 1) {
            float y = __shfl_down(S, off, 64);
            if (lane + off < 64) S += y;
        }
        float Tsuf = S - T;

        // per-lane contributions (6 floats)
        float nq[3], kq[3];
        m3v(nq, N, qv);
        m3v(kq, K2a, qv);
        float t1[3] = { u[0] - M1v[0] - nq[0] - nnv[0],
                        u[1] - M1v[1] - nq[1] - nnv[1],
                        u[2] - M1v[2] - nq[2] - nnv[2] };
        float t2[3] = { z[0] - K1v[0] - kq[0] - k2bv[0],
                        z[1] - K1v[1] - kq[1] - k2bv[1],
                        z[2] - K1v[2] - kq[2] - k2bv[2] };
        float bc[3], ac[3];
        m3v(bc, R, t1);
        m3v(ac, R, t2);
        ac[0] += Tsuf*bc[0]; ac[1] += Tsuf*bc[1]; ac[2] += Tsuf*bc[2];

        #pragma unroll
        for (int off = 1; off < 64; off <<= 1) {
            #pragma unroll
            for (int i = 0; i < 3; ++i) {
                bc[i] += __shfl_xor(bc[i], off, 64);
                ac[i] += __shfl_xor(ac[i], off, 64);
            }
        }

        if (lane == 0) {
            float dthx = 0.5f*Q2fv[0], dthy = 0.5f*Q2fv[1], dthz = 0.5f*Q2fv[2];
            Q4 dq = {dthx, dthy, dthz, 1.0f};
            Q4 gamma = qmul(qf, dq);
            g_gamma[m*4+0] = gamma.x; g_gamma[m*4+1] = gamma.y;
            g_gamma[m*4+2] = gamma.z; g_gamma[m*4+3] = gamma.w;
            g_beta[m*3+0] = bc[0];  g_beta[m*3+1] = bc[1];  g_beta[m*3+2] = bc[2];
            g_alpha[m*3+0] = ac[0]; g_alpha[m*3+1] = ac[1]; g_alpha[m*3+2] = ac[2];
            g_kf[m] = S;
        }
    }

    cg::this_grid().sync();

    // ================= PHASE 2 (block 0) =================
    if (blockIdx.x != 0) return;
    {
        const int tid  = threadIdx.x;
        const int lane = tid & 63;
        const int w    = tid >> 6;

        Q4 qinit = {init_rot[0], init_rot[1], init_rot[2], init_rot[3]};

        Q4 q = {g_gamma[tid*4+0], g_gamma[tid*4+1], g_gamma[tid*4+2], g_gamma[tid*4+3]};
        #pragma unroll
        for (int off = 1; off < 64; off <<= 1) {
            Q4 y;
            y.x = __shfl_up(q.x, off, 64);
            y.y = __shfl_up(q.y, off, 64);
            y.z = __shfl_up(q.z, off, 64);
            y.w = __shfl_up(q.w, off, 64);
            if (lane >= off) q = qmul(y, q);
        }
        if (lane == 63) qtot[w] = make_float4(q.x, q.y, q.z, q.w);
        __syncthreads();
        {
            Q4 pre = {0.f, 0.f, 0.f, 1.f};
            for (int j = 0; j < w; ++j) {
                float4 tq = qtot[j];
                pre = qmul(pre, Q4{tq.x, tq.y, tq.z, tq.w});
            }
            q = qmul(pre, q);
        }
        Q4 rot = qmul(qinit, q);
        srot[tid+1] = make_float4(rot.x, rot.y, rot.z, rot.w);
        if (tid == 0) srot[0] = make_float4(qinit.x, qinit.y, qinit.z, qinit.w);
        __syncthreads();

        const float gx = g[0], gy = g[1], gz = g[2];
        const float iv0 = init_vel[0], iv1 = init_vel[1], iv2 = init_vel[2];
        const float ip0 = init_pos[0], ip1 = init_pos[1], ip2 = init_pos[2];

        float4 r4 = srot[tid];
        Q4 rq = {r4.x, r4.y, r4.z, r4.w};
        float Rw[9]; q2m(rq, Rw);
        float kf = g_kf[tid];
        float bx = g_beta[tid*3+0], by = g_beta[tid*3+1], bz = g_beta[tid*3+2];
        float axm = g_alpha[tid*3+0], aym = g_alpha[tid*3+1], azm = g_alpha[tid*3+2];

        float dv0 = -gx*kf + Rw[0]*bx + Rw[1]*by + Rw[2]*bz;
        float dv1 = -gy*kf + Rw[3]*bx + Rw[4]*by + Rw[5]*bz;
        float dv2 = -gz*kf + Rw[6]*bx + Rw[7]*by + Rw[8]*bz;
        float s0 = dv0, s1 = dv1, s2 = dv2;
        #pragma unroll
        for (int off = 1; off < 64; off <<= 1) {
            float y0 = __shfl_up(s0, off, 64);
            float y1 = __shfl_up(s1, off, 64);
            float y2 = __shfl_up(s2, off, 64);
            if (lane >= off) { s0 += y0; s1 += y1; s2 += y2; }
        }
        if (lane == 63) { vtot[w][0] = s0; vtot[w][1] = s1; vtot[w][2] = s2; }
        __syncthreads();
        {
            float p0 = 0.f, p1 = 0.f, p2 = 0.f;
            for (int j = 0; j < w; ++j) { p0 += vtot[j][0]; p1 += vtot[j][1]; p2 += vtot[j][2]; }
            s0 += p0; s1 += p1; s2 += p2;
        }
        svel[tid+1][0] = iv0 + s0; svel[tid+1][1] = iv1 + s1; svel[tid+1][2] = iv2 + s2;
        if (tid == 0) { svel[0][0] = iv0; svel[0][1] = iv1; svel[0][2] = iv2; }

        float vm0 = iv0 + s0 - dv0, vm1 = iv1 + s1 - dv1, vm2 = iv2 + s2 - dv2;

        float dp0 = vm0*kf - 0.5f*gx*kf*kf + Rw[0]*axm + Rw[1]*aym + Rw[2]*azm;
        float dp1 = vm1*kf - 0.5f*gy*kf*kf + Rw[3]*axm + Rw[4]*aym + Rw[5]*azm;
        float dp2 = vm2*kf - 0.5f*gz*kf*kf + Rw[6]*axm + Rw[7]*aym + Rw[8]*azm;
        float t0 = dp0, t1 = dp1, t2 = dp2;
        #pragma unroll
        for (int off = 1; off < 64; off <<= 1) {
            float y0 = __shfl_up(t0, off, 64);
            float y1 = __shfl_up(t1, off, 64);
            float y2 = __shfl_up(t2, off, 64);
            if (lane >= off) { t0 += y0; t1 += y1; t2 += y2; }
        }
        if (lane == 63) { ptot[w][0] = t0; ptot[w][1] = t1; ptot[w][2] = t2; }
        __syncthreads();
        {
            float p0 = 0.f, p1 = 0.f, p2 = 0.f;
            for (int j = 0; j < w; ++j) { p0 += ptot[j][0]; p1 += ptot[j][1]; p2 += ptot[j][2]; }
            t0 += p0; t1 += p1; t2 += p2;
        }
        spos[tid+1][0] = ip0 + t0; spos[tid+1][1] = ip1 + t1; spos[tid+1][2] = ip2 + t2;
        if (tid == 0) { spos[0][0] = ip0; spos[0][1] = ip1; spos[0][2] = ip2; }
        __syncthreads();

        for (int k = tid; k < NK; k += 1024) {
            float4 rr = srot[k];
            Q4 rk = {rr.x, rr.y, rr.z, rr.w};
            Q4 gc = {-gt_rot[k*4+0], -gt_rot[k*4+1], -gt_rot[k*4+2], gt_rot[k*4+3]};
            Q4 e = qmul(gc, rk);
            float n2 = e.x*e.x + e.y*e.y + e.z*e.z;
            float n = sqrtf(n2);
            float theta = 2.f*atan2f(n, e.w);
            float scale;
            if (n < 1e-6f) {
                float wd = (fabsf(e.w) < 1e-6f) ? 1.f : e.w;
                scale = 2.f/wd;
            } else {
                scale = theta/n;
            }
            out[k*3+0] = e.x*scale;
            out[k*3+1] = e.y*scale;
            out[k*3+2] = e.z*scale;

            float d0 = gt_pos[k*3+0] - spos[k][0];
            float d1 = gt_pos[k*3+1] - spos[k][1];
            float d2 = gt_pos[k*3+2] - spos[k][2];
            out[(NK+k)*3+0] = d0*d0;
            out[(NK+k)*3+1] = d1*d1;
            out[(NK+k)*3+2] = d2*d2;

            float e0 = gt_vel[k*3+0] - svel[k][0];
            float e1 = gt_vel[k*3+1] - svel[k][1];
            float e2 = gt_vel[k*3+2] - svel[k][2];
            out[(2*NK+k)*3+0] = e0*e0;
            out[(2*NK+k)*3+1] = e1*e1;
            out[(2*NK+k)*3+2] = e2*e2;
        }
    }
}

extern "C" void kernel_launch(void* const* d_in, const int* in_sizes, int n_in,
                              void* d_out, int out_size, void* d_ws, size_t ws_size,
                              hipStream_t stream) {
    const float* acc      = (const float*)d_in[0];
    const float* gyro     = (const float*)d_in[1];
    const float* dt       = (const float*)d_in[2];
    const float* bias_a   = (const float*)d_in[3];
    const float* bias_w   = (const float*)d_in[4];
    const float* g        = (const float*)d_in[5];
    const float* init_rot = (const float*)d_in[6];
    const float* init_pos = (const float*)d_in[7];
    const float* init_vel = (const float*)d_in[8];
    const float* gt_rot   = (const float*)d_in[9];
    const float* gt_pos   = (const float*)d_in[10];
    const float* gt_vel   = (const float*)d_in[11];
    float* ws  = (float*)d_ws;
    float* out = (float*)d_out;

    void* kargs[] = {
        (void*)&acc, (void*)&gyro, (void*)&dt, (void*)&bias_a, (void*)&bias_w,
        (void*)&ws, (void*)&g, (void*)&init_rot, (void*)&init_pos, (void*)&init_vel,
        (void*)&gt_rot, (void*)&gt_pos, (void*)&gt_vel, (void*)&out
    };
    hipLaunchCooperativeKernel((void*)imu_fused, dim3(NM/16), dim3(1024),
                               kargs, 0, stream);
}

// Round 10
// 57.088 us; speedup vs baseline: 1.0101x; 1.0101x over previous
//
#include <hip/hip_runtime.h>
#include <hip/hip_cooperative_groups.h>
#include <math.h>

namespace cg = cooperative_groups;

#define NM 1024
#define NS 256
#define NK 1025
#define CS 4    // steps per chunk
#define NC 64   // chunks per sequence = lanes per wave

struct Q4 { float x, y, z, w; };

__device__ __forceinline__ Q4 qmul(const Q4 a, const Q4 b) {
    Q4 o;
    o.x = a.w*b.x + a.x*b.w + a.y*b.z - a.z*b.y;
    o.y = a.w*b.y - a.x*b.z + a.y*b.w + a.z*b.x;
    o.z = a.w*b.z + a.x*b.y - a.y*b.x + a.z*b.w;
    o.w = a.w*b.w - a.x*b.x - a.y*b.y - a.z*b.z;
    return o;
}

__device__ __forceinline__ void q2m(const Q4 q, float* R) {
    float x = q.x, y = q.y, z = q.z, w = q.w;
    R[0] = 1.f - 2.f*(y*y + z*z); R[1] = 2.f*(x*y - z*w);       R[2] = 2.f*(x*z + y*w);
    R[3] = 2.f*(x*y + z*w);       R[4] = 1.f - 2.f*(x*x + z*z); R[5] = 2.f*(y*z - x*w);
    R[6] = 2.f*(x*z - y*w);       R[7] = 2.f*(y*z + x*w);       R[8] = 1.f - 2.f*(x*x + y*y);
}

__device__ __forceinline__ void m3mul(float* o, const float* X, const float* Y) {
    #pragma unroll
    for (int r = 0; r < 3; ++r)
        #pragma unroll
        for (int c = 0; c < 3; ++c)
            o[r*3+c] = X[r*3+0]*Y[c] + X[r*3+1]*Y[3+c] + X[r*3+2]*Y[6+c];
}

__device__ __forceinline__ void m3v(float* o, const float* X, const float* v) {
    o[0] = X[0]*v[0] + X[1]*v[1] + X[2]*v[2];
    o[1] = X[3]*v[0] + X[4]*v[1] + X[5]*v[2];
    o[2] = X[6]*v[0] + X[7]*v[1] + X[8]*v[2];
}

__device__ __forceinline__ void skmul(float* o, float x, float y, float z, const float* M) {
    #pragma unroll
    for (int c = 0; c < 3; ++c) {
        float m0 = M[c], m1 = M[3+c], m2 = M[6+c];
        o[c]   = -z*m1 + y*m2;
        o[3+c] =  z*m0 - x*m2;
        o[6+c] = -y*m0 + x*m1;
    }
}

__device__ __forceinline__ void crossv(float* o, float x, float y, float z, const float* v) {
    o[0] = -z*v[1] + y*v[2];
    o[1] =  z*v[0] - x*v[2];
    o[2] = -y*v[0] + x*v[1];
}

__device__ __forceinline__ void ld12(float* dst, const float4* src) {
    float4 t0 = src[0], t1 = src[1], t2 = src[2];
    dst[0]=t0.x; dst[1]=t0.y; dst[2] =t0.z; dst[3] =t0.w;
    dst[4]=t1.x; dst[5]=t1.y; dst[6] =t1.z; dst[7] =t1.w;
    dst[8]=t2.x; dst[9]=t2.y; dst[10]=t2.z; dst[11]=t2.w;
}

// ------------------------------------------------------------------
// Fused kernel: 64 blocks x 1024 threads (cooperative).
// Phase 1: wave-per-sequence (16 per block), bias-contracted scan
// formulation (verified R8). grid.sync(). Phase 2: block 0 only.
// NOTE: __launch_bounds__(1024) with NO min-waves arg — R9's (1024,4)
// capped VGPR at 64 and spilled (+4MB scratch traffic, 2.8x slower).
// A 1024-thread block implies a 128-VGPR cap, enough for the ~104
// this body needs.
// ------------------------------------------------------------------
__global__ __launch_bounds__(1024) void imu_fused(
    const float* __restrict__ acc, const float* __restrict__ gyro,
    const float* __restrict__ dt, const float* __restrict__ bias_a,
    const float* __restrict__ bias_w, float* __restrict__ ws,
    const float* __restrict__ g, const float* __restrict__ init_rot,
    const float* __restrict__ init_pos, const float* __restrict__ init_vel,
    const float* __restrict__ gt_rot, const float* __restrict__ gt_pos,
    const float* __restrict__ gt_vel, float* __restrict__ out)
{
    // phase-2 LDS (used by block 0 only; 41.6 KB)
    __shared__ float4 srot[NK];
    __shared__ float  svel[NK][3];
    __shared__ float  spos[NK][3];
    __shared__ float4 qtot[16];
    __shared__ float  vtot[16][3];
    __shared__ float  ptot[16][3];

    float* g_gamma = ws;            // NM*4
    float* g_beta  = ws + 4*NM;     // NM*3
    float* g_alpha = ws + 7*NM;     // NM*3
    float* g_kf    = ws + 10*NM;    // NM

    // ================= PHASE 1 =================
    {
        const int lane = threadIdx.x & 63;
        const int m    = blockIdx.x * 16 + (threadIdx.x >> 6);
        const int c    = lane;

        float av[12], gv[12], bav[12], bwv[12], dtv[4];
        ld12(av,  (const float4*)(acc    + (size_t)m*NS*3) + c*3);
        ld12(gv,  (const float4*)(gyro   + (size_t)m*NS*3) + c*3);
        ld12(bav, (const float4*)(bias_a + (size_t)m*NS*3) + c*3);
        ld12(bwv, (const float4*)(bias_w + (size_t)m*NS*3) + c*3);
        {
            float4 t = ((const float4*)(dt + (size_t)m*NS))[c];
            dtv[0]=t.x; dtv[1]=t.y; dtv[2]=t.z; dtv[3]=t.w;
        }

        float ba0[3], bw0[3];
        ba0[0] = __shfl(bav[0], 0, 64); ba0[1] = __shfl(bav[1], 0, 64); ba0[2] = __shfl(bav[2], 0, 64);
        bw0[0] = __shfl(bwv[0], 0, 64); bw0[1] = __shfl(bwv[1], 0, 64); bw0[2] = __shfl(bwv[2], 0, 64);

        Q4 fq = {0.f, 0.f, 0.f, 1.f};
        float G[9] = {1.f,0.f,0.f, 0.f,1.f,0.f, 0.f,0.f,1.f};
        float T = 0.f;
        float u[3] = {0.f}, z[3] = {0.f};
        float A[9]  = {1.f,0.f,0.f, 0.f,1.f,0.f, 0.f,0.f,1.f};
        float Bmv[3] = {0.f};
        float M1v[3] = {0.f}, N[9] = {0.f}, nnv[3] = {0.f};
        float K1v[3] = {0.f}, K2a[9] = {0.f}, k2bv[3] = {0.f};

        #pragma unroll
        for (int j = 0; j < CS; ++j) {
            float d  = dtv[j];
            float ax = av[j*3+0], ay = av[j*3+1], az = av[j*3+2];
            float gx = gv[j*3+0], gy = gv[j*3+1], gz = gv[j*3+2];
            float abx = ax - bav[j*3+0], aby = ay - bav[j*3+1], abz = az - bav[j*3+2];
            float wbx = gx - bwv[j*3+0], wby = gy - bwv[j*3+1], wbz = gz - bwv[j*3+2];

            #pragma unroll
            for (int i = 0; i < 3; ++i) { K1v[i] += d*M1v[i]; k2bv[i] += d*nnv[i]; }
            #pragma unroll
            for (int i = 0; i < 9; ++i) K2a[i] += d*N[i];

            float ga0 = G[0]*ax + G[1]*ay + G[2]*az;
            float ga1 = G[3]*ax + G[4]*ay + G[5]*az;
            float ga2 = G[6]*ax + G[7]*ay + G[8]*az;
            float hd2 = 0.5f*d*d;
            z[0] += d*u[0] + hd2*ga0;
            z[1] += d*u[1] + hd2*ga1;
            z[2] += d*u[2] + hd2*ga2;
            u[0] += d*ga0; u[1] += d*ga1; u[2] += d*ga2;
            T += d;

            float phx = gx*d, phy = gy*d, phz = gz*d;
            float th2 = phx*phx + phy*phy + phz*phz;
            float k  = 0.5f - th2*(1.0f/48.0f);
            float ew = 1.0f - th2*0.125f;
            Q4 e = {phx*k, phy*k, phz*k, ew};
            fq = qmul(fq, e);
            q2m(fq, G);

            {
                float gb[3]; m3v(gb, G, ba0);
                M1v[0] += d*gb[0]; M1v[1] += d*gb[1]; M1v[2] += d*gb[2];
            }
            {
                float SA[9], GX[9];
                skmul(SA, abx, aby, abz, A);
                m3mul(GX, G, SA);
                #pragma unroll
                for (int i = 0; i < 9; ++i) N[i] += d*GX[i];
            }
            {
                float cb[3], gc[3];
                crossv(cb, abx, aby, abz, Bmv);
                m3v(gc, G, cb);
                nnv[0] += d*gc[0]; nnv[1] += d*gc[1]; nnv[2] += d*gc[2];
            }
            {
                float WA[9];
                skmul(WA, wbx, wby, wbz, A);
                #pragma unroll
                for (int i = 0; i < 9; ++i) A[i] -= d*WA[i];
            }
            {
                float cw[3];
                crossv(cw, wbx, wby, wbz, Bmv);
                Bmv[0] -= d*(cw[0] + bw0[0]);
                Bmv[1] -= d*(cw[1] + bw0[1]);
                Bmv[2] -= d*(cw[2] + bw0[2]);
            }
        }

        // scan 1: quat inclusive prefix -> final + exclusive
        Q4 qi = fq;
        #pragma unroll
        for (int off = 1; off < 64; off <<= 1) {
            Q4 y;
            y.x = __shfl_up(qi.x, off, 64);
            y.y = __shfl_up(qi.y, off, 64);
            y.z = __shfl_up(qi.z, off, 64);
            y.w = __shfl_up(qi.w, off, 64);
            if (lane >= off) qi = qmul(y, qi);
        }
        Q4 qf;
        qf.x = __shfl(qi.x, 63, 64);
        qf.y = __shfl(qi.y, 63, 64);
        qf.z = __shfl(qi.z, 63, 64);
        qf.w = __shfl(qi.w, 63, 64);
        Q4 qp;
        qp.x = __shfl_up(qi.x, 1, 64);
        qp.y = __shfl_up(qi.y, 1, 64);
        qp.z = __shfl_up(qi.z, 1, 64);
        qp.w = __shfl_up(qi.w, 1, 64);
        if (lane == 0) { qp.x = 0.f; qp.y = 0.f; qp.z = 0.f; qp.w = 1.f; }
        float R[9]; q2m(qp, R);

        // scan 2: affine (A, bvec) inclusive prefix
        float bvec[3] = {Bmv[0], Bmv[1], Bmv[2]};
        #pragma unroll
        for (int off = 1; off < 64; off <<= 1) {
            float yA[9], yb[3];
            #pragma unroll
            for (int i = 0; i < 9; ++i) yA[i] = __shfl_up(A[i], off, 64);
            yb[0] = __shfl_up(bvec[0], off, 64);
            yb[1] = __shfl_up(bvec[1], off, 64);
            yb[2] = __shfl_up(bvec[2], off, 64);
            if (lane >= off) {
                float nA[9], nb[3];
                m3mul(nA, A, yA);
                m3v(nb, A, yb);
                #pragma unroll
                for (int i = 0; i < 9; ++i) A[i] = nA[i];
                bvec[0] = nb[0] + bvec[0];
                bvec[1] = nb[1] + bvec[1];
                bvec[2] = nb[2] + bvec[2];
            }
        }
        float Q2fv[3];
        Q2fv[0] = __shfl(bvec[0], 63, 64);
        Q2fv[1] = __shfl(bvec[1], 63, 64);
        Q2fv[2] = __shfl(bvec[2], 63, 64);
        float qv[3];
        qv[0] = __shfl_up(bvec[0], 1, 64);
        qv[1] = __shfl_up(bvec[1], 1, 64);
        qv[2] = __shfl_up(bvec[2], 1, 64);
        if (lane == 0) { qv[0] = 0.f; qv[1] = 0.f; qv[2] = 0.f; }

        // scan 3: T inclusive suffix sum
        float S = T;
        #pragma unroll
        for (int off = 1; off < 64; off <<= 1) {
            float y = __shfl_down(S, off, 64);
            if (lane + off < 64) S += y;
        }
        float Tsuf = S - T;

        // per-lane contributions (6 floats)
        float nq[3], kq[3];
        m3v(nq, N, qv);
        m3v(kq, K2a, qv);
        float t1[3] = { u[0] - M1v[0] - nq[0] - nnv[0],
                        u[1] - M1v[1] - nq[1] - nnv[1],
                        u[2] - M1v[2] - nq[2] - nnv[2] };
        float t2[3] = { z[0] - K1v[0] - kq[0] - k2bv[0],
                        z[1] - K1v[1] - kq[1] - k2bv[1],
                        z[2] - K1v[2] - kq[2] - k2bv[2] };
        float bc[3], ac[3];
        m3v(bc, R, t1);
        m3v(ac, R, t2);
        ac[0] += Tsuf*bc[0]; ac[1] += Tsuf*bc[1]; ac[2] += Tsuf*bc[2];

        #pragma unroll
        for (int off = 1; off < 64; off <<= 1) {
            #pragma unroll
            for (int i = 0; i < 3; ++i) {
                bc[i] += __shfl_xor(bc[i], off, 64);
                ac[i] += __shfl_xor(ac[i], off, 64);
            }
        }

        if (lane == 0) {
            float dthx = 0.5f*Q2fv[0], dthy = 0.5f*Q2fv[1], dthz = 0.5f*Q2fv[2];
            Q4 dq = {dthx, dthy, dthz, 1.0f};
            Q4 gamma = qmul(qf, dq);
            g_gamma[m*4+0] = gamma.x; g_gamma[m*4+1] = gamma.y;
            g_gamma[m*4+2] = gamma.z; g_gamma[m*4+3] = gamma.w;
            g_beta[m*3+0] = bc[0];  g_beta[m*3+1] = bc[1];  g_beta[m*3+2] = bc[2];
            g_alpha[m*3+0] = ac[0]; g_alpha[m*3+1] = ac[1]; g_alpha[m*3+2] = ac[2];
            g_kf[m] = S;
        }
    }

    cg::this_grid().sync();

    // ================= PHASE 2 (block 0) =================
    if (blockIdx.x != 0) return;
    {
        const int tid  = threadIdx.x;
        const int lane = tid & 63;
        const int w    = tid >> 6;

        Q4 qinit = {init_rot[0], init_rot[1], init_rot[2], init_rot[3]};

        Q4 q = {g_gamma[tid*4+0], g_gamma[tid*4+1], g_gamma[tid*4+2], g_gamma[tid*4+3]};
        #pragma unroll
        for (int off = 1; off < 64; off <<= 1) {
            Q4 y;
            y.x = __shfl_up(q.x, off, 64);
            y.y = __shfl_up(q.y, off, 64);
            y.z = __shfl_up(q.z, off, 64);
            y.w = __shfl_up(q.w, off, 64);
            if (lane >= off) q = qmul(y, q);
        }
        if (lane == 63) qtot[w] = make_float4(q.x, q.y, q.z, q.w);
        __syncthreads();
        {
            Q4 pre = {0.f, 0.f, 0.f, 1.f};
            for (int j = 0; j < w; ++j) {
                float4 tq = qtot[j];
                pre = qmul(pre, Q4{tq.x, tq.y, tq.z, tq.w});
            }
            q = qmul(pre, q);
        }
        Q4 rot = qmul(qinit, q);
        srot[tid+1] = make_float4(rot.x, rot.y, rot.z, rot.w);
        if (tid == 0) srot[0] = make_float4(qinit.x, qinit.y, qinit.z, qinit.w);
        __syncthreads();

        const float gx = g[0], gy = g[1], gz = g[2];
        const float iv0 = init_vel[0], iv1 = init_vel[1], iv2 = init_vel[2];
        const float ip0 = init_pos[0], ip1 = init_pos[1], ip2 = init_pos[2];

        float4 r4 = srot[tid];
        Q4 rq = {r4.x, r4.y, r4.z, r4.w};
        float Rw[9]; q2m(rq, Rw);
        float kf = g_kf[tid];
        float bx = g_beta[tid*3+0], by = g_beta[tid*3+1], bz = g_beta[tid*3+2];
        float axm = g_alpha[tid*3+0], aym = g_alpha[tid*3+1], azm = g_alpha[tid*3+2];

        float dv0 = -gx*kf + Rw[0]*bx + Rw[1]*by + Rw[2]*bz;
        float dv1 = -gy*kf + Rw[3]*bx + Rw[4]*by + Rw[5]*bz;
        float dv2 = -gz*kf + Rw[6]*bx + Rw[7]*by + Rw[8]*bz;
        float s0 = dv0, s1 = dv1, s2 = dv2;
        #pragma unroll
        for (int off = 1; off < 64; off <<= 1) {
            float y0 = __shfl_up(s0, off, 64);
            float y1 = __shfl_up(s1, off, 64);
            float y2 = __shfl_up(s2, off, 64);
            if (lane >= off) { s0 += y0; s1 += y1; s2 += y2; }
        }
        if (lane == 63) { vtot[w][0] = s0; vtot[w][1] = s1; vtot[w][2] = s2; }
        __syncthreads();
        {
            float p0 = 0.f, p1 = 0.f, p2 = 0.f;
            for (int j = 0; j < w; ++j) { p0 += vtot[j][0]; p1 += vtot[j][1]; p2 += vtot[j][2]; }
            s0 += p0; s1 += p1; s2 += p2;
        }
        svel[tid+1][0] = iv0 + s0; svel[tid+1][1] = iv1 + s1; svel[tid+1][2] = iv2 + s2;
        if (tid == 0) { svel[0][0] = iv0; svel[0][1] = iv1; svel[0][2] = iv2; }

        float vm0 = iv0 + s0 - dv0, vm1 = iv1 + s1 - dv1, vm2 = iv2 + s2 - dv2;

        float dp0 = vm0*kf - 0.5f*gx*kf*kf + Rw[0]*axm + Rw[1]*aym + Rw[2]*azm;
        float dp1 = vm1*kf - 0.5f*gy*kf*kf + Rw[3]*axm + Rw[4]*aym + Rw[5]*azm;
        float dp2 = vm2*kf - 0.5f*gz*kf*kf + Rw[6]*axm + Rw[7]*aym + Rw[8]*azm;
        float t0 = dp0, t1 = dp1, t2 = dp2;
        #pragma unroll
        for (int off = 1; off < 64; off <<= 1) {
            float y0 = __shfl_up(t0, off, 64);
            float y1 = __shfl_up(t1, off, 64);
            float y2 = __shfl_up(t2, off, 64);
            if (lane >= off) { t0 += y0; t1 += y1; t2 += y2; }
        }
        if (lane == 63) { ptot[w][0] = t0; ptot[w][1] = t1; ptot[w][2] = t2; }
        __syncthreads();
        {
            float p0 = 0.f, p1 = 0.f, p2 = 0.f;
            for (int j = 0; j < w; ++j) { p0 += ptot[j][0]; p1 += ptot[j][1]; p2 += ptot[j][2]; }
            t0 += p0; t1 += p1; t2 += p2;
        }
        spos[tid+1][0] = ip0 + t0; spos[tid+1][1] = ip1 + t1; spos[tid+1][2] = ip2 + t2;
        if (tid == 0) { spos[0][0] = ip0; spos[0][1] = ip1; spos[0][2] = ip2; }
        __syncthreads();

        for (int k = tid; k < NK; k += 1024) {
            float4 rr = srot[k];
            Q4 rk = {rr.x, rr.y, rr.z, rr.w};
            Q4 gc = {-gt_rot[k*4+0], -gt_rot[k*4+1], -gt_rot[k*4+2], gt_rot[k*4+3]};
            Q4 e = qmul(gc, rk);
            float n2 = e.x*e.x + e.y*e.y + e.z*e.z;
            float n = sqrtf(n2);
            float theta = 2.f*atan2f(n, e.w);
            float scale;
            if (n < 1e-6f) {
                float wd = (fabsf(e.w) < 1e-6f) ? 1.f : e.w;
                scale = 2.f/wd;
            } else {
                scale = theta/n;
            }
            out[k*3+0] = e.x*scale;
            out[k*3+1] = e.y*scale;
            out[k*3+2] = e.z*scale;

            float d0 = gt_pos[k*3+0] - spos[k][0];
            float d1 = gt_pos[k*3+1] - spos[k][1];
            float d2 = gt_pos[k*3+2] - spos[k][2];
            out[(NK+k)*3+0] = d0*d0;
            out[(NK+k)*3+1] = d1*d1;
            out[(NK+k)*3+2] = d2*d2;

            float e0 = gt_vel[k*3+0] - svel[k][0];
            float e1 = gt_vel[k*3+1] - svel[k][1];
            float e2 = gt_vel[k*3+2] - svel[k][2];
            out[(2*NK+k)*3+0] = e0*e0;
            out[(2*NK+k)*3+1] = e1*e1;
            out[(2*NK+k)*3+2] = e2*e2;
        }
    }
}

extern "C" void kernel_launch(void* const* d_in, const int* in_sizes, int n_in,
                              void* d_out, int out_size, void* d_ws, size_t ws_size,
                              hipStream_t stream) {
    const float* acc      = (const float*)d_in[0];
    const float* gyro     = (const float*)d_in[1];
    const float* dt       = (const float*)d_in[2];
    const float* bias_a   = (const float*)d_in[3];
    const float* bias_w   = (const float*)d_in[4];
    const float* g        = (const float*)d_in[5];
    const float* init_rot = (const float*)d_in[6];
    const float* init_pos = (const float*)d_in[7];
    const float* init_vel = (const float*)d_in[8];
    const float* gt_rot   = (const float*)d_in[9];
    const float* gt_pos   = (const float*)d_in[10];
    const float* gt_vel   = (const float*)d_in[11];
    float* ws  = (float*)d_ws;
    float* out = (float*)d_out;

    void* kargs[] = {
        (void*)&acc, (void*)&gyro, (void*)&dt, (void*)&bias_a, (void*)&bias_w,
        (void*)&ws, (void*)&g, (void*)&init_rot, (void*)&init_pos, (void*)&init_vel,
        (void*)&gt_rot, (void*)&gt_pos, (void*)&gt_vel, (void*)&out
    };
    hipLaunchCooperativeKernel((void*)imu_fused, dim3(NM/16), dim3(1024),
                               kargs, 0, stream);
}

// Round 11
// 26.406 us; speedup vs baseline: 2.1838x; 2.1620x over previous
//
#include <hip/hip_runtime.h>
#include <math.h>

#define NM 1024
#define NS 256
#define NK 1025
#define WPS 4   // waves per sequence; lane-per-step, 64 steps per wave

struct Q4 { float x, y, z, w; };

__device__ __forceinline__ Q4 qmul(const Q4 a, const Q4 b) {
    Q4 o;
    o.x = a.w*b.x + a.x*b.w + a.y*b.z - a.z*b.y;
    o.y = a.w*b.y - a.x*b.z + a.y*b.w + a.z*b.x;
    o.z = a.w*b.z + a.x*b.y - a.y*b.x + a.z*b.w;
    o.w = a.w*b.w - a.x*b.x - a.y*b.y - a.z*b.z;
    return o;
}

__device__ __forceinline__ void q2m(const Q4 q, float* R) {
    float x = q.x, y = q.y, z = q.z, w = q.w;
    R[0] = 1.f - 2.f*(y*y + z*z); R[1] = 2.f*(x*y - z*w);       R[2] = 2.f*(x*z + y*w);
    R[3] = 2.f*(x*y + z*w);       R[4] = 1.f - 2.f*(x*x + z*z); R[5] = 2.f*(y*z - x*w);
    R[6] = 2.f*(x*z - y*w);       R[7] = 2.f*(y*z + x*w);       R[8] = 1.f - 2.f*(x*x + y*y);
}

__device__ __forceinline__ void m3mul(float* o, const float* X, const float* Y) {
    #pragma unroll
    for (int r = 0; r < 3; ++r)
        #pragma unroll
        for (int c = 0; c < 3; ++c)
            o[r*3+c] = X[r*3+0]*Y[c] + X[r*3+1]*Y[3+c] + X[r*3+2]*Y[6+c];
}

__device__ __forceinline__ void m3v(float* o, const float* X, const float* v) {
    o[0] = X[0]*v[0] + X[1]*v[1] + X[2]*v[2];
    o[1] = X[3]*v[0] + X[4]*v[1] + X[5]*v[2];
    o[2] = X[6]*v[0] + X[7]*v[1] + X[8]*v[2];
}

// ------------------------------------------------------------------
// Phase 1: one BLOCK (256 thr = 4 waves) per sequence; one LANE per
// step (CS=1). Leaf fields per step s (bias-contracted; from the
// verified R8 recurrences with a 1-step chunk — K1v/K2a/k2bv/nnv = 0):
//   E=exp(w d), G=mat(E), T=d, u=d*a, z=.5d^2*a,
//   M1v=d*G@ba0, N=d*G@S(a-ba), A=I-d*S(w-bw), b=-d*bw0
// Within-wave scans (quat+T prefix; affine (A,b) prefix), then
// cross-wave combine via LDS:
//   qv_glob = qv_loc + Aexc@bprev_w ;  bprev_{w+1} = A_w@bprev_w + b_w
//   beta  = Σ_w Rpre_w @ BC_w
//   alpha = Σ_w Rpre_w @ (AC_w + TsufW_w*BC_w)
//   qf = E0⊗E1⊗E2⊗E3 ; Q2fv = fold(A,b) ; kf = ΣT_w
// (w=0-only case reduces exactly to the verified R8 formulation.)
// ------------------------------------------------------------------
__global__ __launch_bounds__(256, 4) void imu_phase1(
    const float* __restrict__ acc, const float* __restrict__ gyro,
    const float* __restrict__ dt, const float* __restrict__ bias_a,
    const float* __restrict__ bias_w, float* __restrict__ ws)
{
    __shared__ float sE[WPS][4];
    __shared__ float sA[WPS][9];
    __shared__ float sb[WPS][3];
    __shared__ float sT[WPS];
    __shared__ float sBC[WPS][3];
    __shared__ float sAC[WPS][3];

    const int tid  = threadIdx.x;
    const int w    = tid >> 6;
    const int lane = tid & 63;
    const int m    = blockIdx.x;
    const int s    = tid;            // step index 0..255

    const size_t b3 = (size_t)m * NS * 3;

    // per-lane step inputs (coalesced: 12B/lane contiguous)
    float d  = dt[(size_t)m * NS + s];
    float a0 = acc[b3 + s*3+0], a1 = acc[b3 + s*3+1], a2 = acc[b3 + s*3+2];
    float g0 = gyro[b3 + s*3+0], g1 = gyro[b3 + s*3+1], g2 = gyro[b3 + s*3+2];
    float bas0 = bias_a[b3 + s*3+0], bas1 = bias_a[b3 + s*3+1], bas2 = bias_a[b3 + s*3+2];
    float bws0 = bias_w[b3 + s*3+0], bws1 = bias_w[b3 + s*3+1], bws2 = bias_w[b3 + s*3+2];
    // uniform bias at step 0
    float ba0x = bias_a[b3+0], ba0y = bias_a[b3+1], ba0z = bias_a[b3+2];
    float bw0x = bias_w[b3+0], bw0y = bias_w[b3+1], bw0z = bias_w[b3+2];

    float abx = a0 - bas0, aby = a1 - bas1, abz = a2 - bas2;
    float wbx = g0 - bws0, wby = g1 - bws1, wbz = g2 - bws2;

    // ---- leaf ----
    float phx = g0*d, phy = g1*d, phz = g2*d;
    float th2 = phx*phx + phy*phy + phz*phz;
    float kq  = 0.5f - th2*(1.0f/48.0f);
    float ew  = 1.0f - th2*0.125f;
    Q4 E = {phx*kq, phy*kq, phz*kq, ew};
    float G[9]; q2m(E, G);

    float u0 = d*a0, u1 = d*a1, u2 = d*a2;
    float hd2 = 0.5f*d*d;
    float z0 = hd2*a0, z1 = hd2*a1, z2 = hd2*a2;

    float M1v[3];
    M1v[0] = d*(G[0]*ba0x + G[1]*ba0y + G[2]*ba0z);
    M1v[1] = d*(G[3]*ba0x + G[4]*ba0y + G[5]*ba0z);
    M1v[2] = d*(G[6]*ba0x + G[7]*ba0y + G[8]*ba0z);

    float N[9];
    N[0] = d*( G[1]*abz - G[2]*aby); N[3] = d*( G[4]*abz - G[5]*aby); N[6] = d*( G[7]*abz - G[8]*aby);
    N[1] = d*(-G[0]*abz + G[2]*abx); N[4] = d*(-G[3]*abz + G[5]*abx); N[7] = d*(-G[6]*abz + G[8]*abx);
    N[2] = d*( G[0]*aby - G[1]*abx); N[5] = d*( G[3]*aby - G[4]*abx); N[8] = d*( G[6]*aby - G[7]*abx);

    float A[9];
    A[0] = 1.f;      A[1] =  d*wbz;  A[2] = -d*wby;
    A[3] = -d*wbz;   A[4] = 1.f;     A[5] =  d*wbx;
    A[6] =  d*wby;   A[7] = -d*wbx;  A[8] = 1.f;
    float bvec[3] = {-d*bw0x, -d*bw0y, -d*bw0z};

    // ---- scan 1: quat prefix (+T as 5th field) ----
    Q4 qi = E; float Ti = d;
    #pragma unroll
    for (int off = 1; off < 64; off <<= 1) {
        Q4 y;
        y.x = __shfl_up(qi.x, off, 64);
        y.y = __shfl_up(qi.y, off, 64);
        y.z = __shfl_up(qi.z, off, 64);
        y.w = __shfl_up(qi.w, off, 64);
        float yT = __shfl_up(Ti, off, 64);
        if (lane >= off) { qi = qmul(y, qi); Ti += yT; }
    }
    float Tw = __shfl(Ti, 63, 64);
    float Tsuf = Tw - Ti;               // exclusive suffix within wave
    Q4 qp;
    qp.x = __shfl_up(qi.x, 1, 64);
    qp.y = __shfl_up(qi.y, 1, 64);
    qp.z = __shfl_up(qi.z, 1, 64);
    qp.w = __shfl_up(qi.w, 1, 64);
    if (lane == 0) { qp.x = 0.f; qp.y = 0.f; qp.z = 0.f; qp.w = 1.f; }
    float Rloc[9]; q2m(qp, Rloc);

    // ---- scan 2: affine (A, b) prefix ----
    #pragma unroll
    for (int off = 1; off < 64; off <<= 1) {
        float yA[9], yb[3];
        #pragma unroll
        for (int i = 0; i < 9; ++i) yA[i] = __shfl_up(A[i], off, 64);
        yb[0] = __shfl_up(bvec[0], off, 64);
        yb[1] = __shfl_up(bvec[1], off, 64);
        yb[2] = __shfl_up(bvec[2], off, 64);
        if (lane >= off) {
            float nA[9], nb[3];
            m3mul(nA, A, yA);
            m3v(nb, A, yb);
            #pragma unroll
            for (int i = 0; i < 9; ++i) A[i] = nA[i];
            bvec[0] = nb[0] + bvec[0];
            bvec[1] = nb[1] + bvec[1];
            bvec[2] = nb[2] + bvec[2];
        }
    }
    // exclusive per-lane
    float qvloc[3], Aexc[9];
    qvloc[0] = __shfl_up(bvec[0], 1, 64);
    qvloc[1] = __shfl_up(bvec[1], 1, 64);
    qvloc[2] = __shfl_up(bvec[2], 1, 64);
    #pragma unroll
    for (int i = 0; i < 9; ++i) Aexc[i] = __shfl_up(A[i], 1, 64);
    if (lane == 0) {
        qvloc[0] = qvloc[1] = qvloc[2] = 0.f;
        Aexc[0] = 1.f; Aexc[1] = 0.f; Aexc[2] = 0.f;
        Aexc[3] = 0.f; Aexc[4] = 1.f; Aexc[5] = 0.f;
        Aexc[6] = 0.f; Aexc[7] = 0.f; Aexc[8] = 1.f;
    }

    // ---- wave totals -> LDS ----
    if (lane == 63) {
        sE[w][0] = qi.x; sE[w][1] = qi.y; sE[w][2] = qi.z; sE[w][3] = qi.w;
        #pragma unroll
        for (int i = 0; i < 9; ++i) sA[w][i] = A[i];
        sb[w][0] = bvec[0]; sb[w][1] = bvec[1]; sb[w][2] = bvec[2];
        sT[w] = Ti;
    }
    __syncthreads();

    // ---- cross-wave prefixes (per-lane, cheap) ----
    float bprev[3] = {0.f, 0.f, 0.f};
    for (int j = 0; j < w; ++j) {
        float t[3]; m3v(t, sA[j], bprev);
        bprev[0] = t[0] + sb[j][0];
        bprev[1] = t[1] + sb[j][1];
        bprev[2] = t[2] + sb[j][2];
    }
    float TsufW = 0.f;
    for (int j = w+1; j < WPS; ++j) TsufW += sT[j];

    // qv_glob = qvloc + Aexc@bprev
    float qv[3]; m3v(qv, Aexc, bprev);
    qv[0] += qvloc[0]; qv[1] += qvloc[1]; qv[2] += qvloc[2];

    // ---- per-lane contributions ----
    float nq[3]; m3v(nq, N, qv);
    float t1[3] = { u0 - M1v[0] - nq[0],
                    u1 - M1v[1] - nq[1],
                    u2 - M1v[2] - nq[2] };
    float t2[3] = { z0, z1, z2 };
    float bc[3], ac[3];
    m3v(bc, Rloc, t1);
    m3v(ac, Rloc, t2);
    ac[0] += Tsuf*bc[0]; ac[1] += Tsuf*bc[1]; ac[2] += Tsuf*bc[2];

    // ---- butterfly within wave ----
    #pragma unroll
    for (int off = 1; off < 64; off <<= 1) {
        #pragma unroll
        for (int i = 0; i < 3; ++i) {
            bc[i] += __shfl_xor(bc[i], off, 64);
            ac[i] += __shfl_xor(ac[i], off, 64);
        }
    }

    // ---- per-wave rotate + stash ----
    if (lane == 0) {
        Q4 qpre = {0.f, 0.f, 0.f, 1.f};
        for (int j = 0; j < w; ++j) {
            Q4 ej = {sE[j][0], sE[j][1], sE[j][2], sE[j][3]};
            qpre = qmul(qpre, ej);
        }
        float Rpre[9]; q2m(qpre, Rpre);
        float t[3] = { ac[0] + TsufW*bc[0], ac[1] + TsufW*bc[1], ac[2] + TsufW*bc[2] };
        float bcp[3], acp[3];
        m3v(bcp, Rpre, bc);
        m3v(acp, Rpre, t);
        sBC[w][0] = bcp[0]; sBC[w][1] = bcp[1]; sBC[w][2] = bcp[2];
        sAC[w][0] = acp[0]; sAC[w][1] = acp[1]; sAC[w][2] = acp[2];
    }
    __syncthreads();

    // ---- final combine (thread 0) ----
    if (tid == 0) {
        float beta[3]  = {0.f, 0.f, 0.f};
        float alpha[3] = {0.f, 0.f, 0.f};
        float kf = 0.f;
        #pragma unroll
        for (int j = 0; j < WPS; ++j) {
            beta[0]  += sBC[j][0]; beta[1]  += sBC[j][1]; beta[2]  += sBC[j][2];
            alpha[0] += sAC[j][0]; alpha[1] += sAC[j][1]; alpha[2] += sAC[j][2];
            kf += sT[j];
        }
        Q4 qf = {sE[0][0], sE[0][1], sE[0][2], sE[0][3]};
        #pragma unroll
        for (int j = 1; j < WPS; ++j) {
            Q4 ej = {sE[j][0], sE[j][1], sE[j][2], sE[j][3]};
            qf = qmul(qf, ej);
        }
        float bfin[3] = {0.f, 0.f, 0.f};
        #pragma unroll
        for (int j = 0; j < WPS; ++j) {
            float t[3]; m3v(t, sA[j], bfin);
            bfin[0] = t[0] + sb[j][0];
            bfin[1] = t[1] + sb[j][1];
            bfin[2] = t[2] + sb[j][2];
        }
        Q4 dq = {0.5f*bfin[0], 0.5f*bfin[1], 0.5f*bfin[2], 1.0f};
        Q4 gamma = qmul(qf, dq);

        float* g_gamma = ws;            // NM*4
        float* g_beta  = ws + 4*NM;     // NM*3
        float* g_alpha = ws + 7*NM;     // NM*3
        float* g_kf    = ws + 10*NM;    // NM
        g_gamma[m*4+0] = gamma.x; g_gamma[m*4+1] = gamma.y;
        g_gamma[m*4+2] = gamma.z; g_gamma[m*4+3] = gamma.w;
        g_beta[m*3+0] = beta[0];  g_beta[m*3+1] = beta[1];  g_beta[m*3+2] = beta[2];
        g_alpha[m*3+0] = alpha[0]; g_alpha[m*3+1] = alpha[1]; g_alpha[m*3+2] = alpha[2];
        g_kf[m] = kf;
    }
}

// ------------------------------------------------------------------
// Phase 2: single block, 1024 threads = 16 waves (unchanged from R8).
// ------------------------------------------------------------------
__global__ __launch_bounds__(1024) void imu_phase2(
    const float* __restrict__ ws, const float* __restrict__ g,
    const float* __restrict__ init_rot, const float* __restrict__ init_pos,
    const float* __restrict__ init_vel, const float* __restrict__ gt_rot,
    const float* __restrict__ gt_pos, const float* __restrict__ gt_vel,
    float* __restrict__ out)
{
    __shared__ float4 srot[NK];
    __shared__ float  svel[NK][3];
    __shared__ float  spos[NK][3];
    __shared__ float4 qtot[16];
    __shared__ float  vtot[16][3];
    __shared__ float  ptot[16][3];

    const int tid  = threadIdx.x;
    const int lane = tid & 63;
    const int w    = tid >> 6;

    const float* g_gamma = ws;
    const float* g_beta  = ws + 4*NM;
    const float* g_alpha = ws + 7*NM;
    const float* g_kf    = ws + 10*NM;

    Q4 qinit = {init_rot[0], init_rot[1], init_rot[2], init_rot[3]};

    Q4 q = {g_gamma[tid*4+0], g_gamma[tid*4+1], g_gamma[tid*4+2], g_gamma[tid*4+3]};
    #pragma unroll
    for (int off = 1; off < 64; off <<= 1) {
        Q4 y;
        y.x = __shfl_up(q.x, off, 64);
        y.y = __shfl_up(q.y, off, 64);
        y.z = __shfl_up(q.z, off, 64);
        y.w = __shfl_up(q.w, off, 64);
        if (lane >= off) q = qmul(y, q);
    }
    if (lane == 63) qtot[w] = make_float4(q.x, q.y, q.z, q.w);
    __syncthreads();
    {
        Q4 pre = {0.f, 0.f, 0.f, 1.f};
        for (int j = 0; j < w; ++j) {
            float4 tq = qtot[j];
            pre = qmul(pre, Q4{tq.x, tq.y, tq.z, tq.w});
        }
        q = qmul(pre, q);
    }
    Q4 rot = qmul(qinit, q);
    srot[tid+1] = make_float4(rot.x, rot.y, rot.z, rot.w);
    if (tid == 0) srot[0] = make_float4(qinit.x, qinit.y, qinit.z, qinit.w);
    __syncthreads();

    const float gx = g[0], gy = g[1], gz = g[2];
    const float iv0 = init_vel[0], iv1 = init_vel[1], iv2 = init_vel[2];
    const float ip0 = init_pos[0], ip1 = init_pos[1], ip2 = init_pos[2];

    float4 r4 = srot[tid];
    Q4 rq = {r4.x, r4.y, r4.z, r4.w};
    float Rw[9]; q2m(rq, Rw);
    float kf = g_kf[tid];
    float bx = g_beta[tid*3+0], by = g_beta[tid*3+1], bz = g_beta[tid*3+2];
    float axm = g_alpha[tid*3+0], aym = g_alpha[tid*3+1], azm = g_alpha[tid*3+2];

    float dv0 = -gx*kf + Rw[0]*bx + Rw[1]*by + Rw[2]*bz;
    float dv1 = -gy*kf + Rw[3]*bx + Rw[4]*by + Rw[5]*bz;
    float dv2 = -gz*kf + Rw[6]*bx + Rw[7]*by + Rw[8]*bz;
    float s0 = dv0, s1 = dv1, s2 = dv2;
    #pragma unroll
    for (int off = 1; off < 64; off <<= 1) {
        float y0 = __shfl_up(s0, off, 64);
        float y1 = __shfl_up(s1, off, 64);
        float y2 = __shfl_up(s2, off, 64);
        if (lane >= off) { s0 += y0; s1 += y1; s2 += y2; }
    }
    if (lane == 63) { vtot[w][0] = s0; vtot[w][1] = s1; vtot[w][2] = s2; }
    __syncthreads();
    {
        float p0 = 0.f, p1 = 0.f, p2 = 0.f;
        for (int j = 0; j < w; ++j) { p0 += vtot[j][0]; p1 += vtot[j][1]; p2 += vtot[j][2]; }
        s0 += p0; s1 += p1; s2 += p2;
    }
    svel[tid+1][0] = iv0 + s0; svel[tid+1][1] = iv1 + s1; svel[tid+1][2] = iv2 + s2;
    if (tid == 0) { svel[0][0] = iv0; svel[0][1] = iv1; svel[0][2] = iv2; }

    float vm0 = iv0 + s0 - dv0, vm1 = iv1 + s1 - dv1, vm2 = iv2 + s2 - dv2;

    float dp0 = vm0*kf - 0.5f*gx*kf*kf + Rw[0]*axm + Rw[1]*aym + Rw[2]*azm;
    float dp1 = vm1*kf - 0.5f*gy*kf*kf + Rw[3]*axm + Rw[4]*aym + Rw[5]*azm;
    float dp2 = vm2*kf - 0.5f*gz*kf*kf + Rw[6]*axm + Rw[7]*aym + Rw[8]*azm;
    float t0 = dp0, t1 = dp1, t2 = dp2;
    #pragma unroll
    for (int off = 1; off < 64; off <<= 1) {
        float y0 = __shfl_up(t0, off, 64);
        float y1 = __shfl_up(t1, off, 64);
        float y2 = __shfl_up(t2, off, 64);
        if (lane >= off) { t0 += y0; t1 += y1; t2 += y2; }
    }
    if (lane == 63) { ptot[w][0] = t0; ptot[w][1] = t1; ptot[w][2] = t2; }
    __syncthreads();
    {
        float p0 = 0.f, p1 = 0.f, p2 = 0.f;
        for (int j = 0; j < w; ++j) { p0 += ptot[j][0]; p1 += ptot[j][1]; p2 += ptot[j][2]; }
        t0 += p0; t1 += p1; t2 += p2;
    }
    spos[tid+1][0] = ip0 + t0; spos[tid+1][1] = ip1 + t1; spos[tid+1][2] = ip2 + t2;
    if (tid == 0) { spos[0][0] = ip0; spos[0][1] = ip1; spos[0][2] = ip2; }
    __syncthreads();

    for (int k = tid; k < NK; k += 1024) {
        float4 rr = srot[k];
        Q4 rk = {rr.x, rr.y, rr.z, rr.w};
        Q4 gc = {-gt_rot[k*4+0], -gt_rot[k*4+1], -gt_rot[k*4+2], gt_rot[k*4+3]};
        Q4 e = qmul(gc, rk);
        float n2 = e.x*e.x + e.y*e.y + e.z*e.z;
        float n = sqrtf(n2);
        float theta = 2.f*atan2f(n, e.w);
        float scale;
        if (n < 1e-6f) {
            float wd = (fabsf(e.w) < 1e-6f) ? 1.f : e.w;
            scale = 2.f/wd;
        } else {
            scale = theta/n;
        }
        out[k*3+0] = e.x*scale;
        out[k*3+1] = e.y*scale;
        out[k*3+2] = e.z*scale;

        float d0 = gt_pos[k*3+0] - spos[k][0];
        float d1 = gt_pos[k*3+1] - spos[k][1];
        float d2 = gt_pos[k*3+2] - spos[k][2];
        out[(NK+k)*3+0] = d0*d0;
        out[(NK+k)*3+1] = d1*d1;
        out[(NK+k)*3+2] = d2*d2;

        float e0 = gt_vel[k*3+0] - svel[k][0];
        float e1 = gt_vel[k*3+1] - svel[k][1];
        float e2 = gt_vel[k*3+2] - svel[k][2];
        out[(2*NK+k)*3+0] = e0*e0;
        out[(2*NK+k)*3+1] = e1*e1;
        out[(2*NK+k)*3+2] = e2*e2;
    }
}

extern "C" void kernel_launch(void* const* d_in, const int* in_sizes, int n_in,
                              void* d_out, int out_size, void* d_ws, size_t ws_size,
                              hipStream_t stream) {
    const float* acc      = (const float*)d_in[0];
    const float* gyro     = (const float*)d_in[1];
    const float* dt       = (const float*)d_in[2];
    const float* bias_a   = (const float*)d_in[3];
    const float* bias_w   = (const float*)d_in[4];
    const float* g        = (const float*)d_in[5];
    const float* init_rot = (const float*)d_in[6];
    const float* init_pos = (const float*)d_in[7];
    const float* init_vel = (const float*)d_in[8];
    const float* gt_rot   = (const float*)d_in[9];
    const float* gt_pos   = (const float*)d_in[10];
    const float* gt_vel   = (const float*)d_in[11];
    float* ws  = (float*)d_ws;
    float* out = (float*)d_out;

    imu_phase1<<<NM, 256, 0, stream>>>(acc, gyro, dt, bias_a, bias_w, ws);
    imu_phase2<<<1, 1024, 0, stream>>>(ws, g, init_rot, init_pos, init_vel,
                                       gt_rot, gt_pos, gt_vel, out);
}